// Round 7
// baseline (468.022 us; speedup 1.0000x reference)
//
#include <hip/hip_runtime.h>
#include <hip/hip_bf16.h>
#include <math.h>

typedef __attribute__((ext_vector_type(4))) short short4v;
typedef __attribute__((ext_vector_type(8))) short short8;
typedef __attribute__((ext_vector_type(16))) float f32x16;

static constexpr int B  = 32;
static constexpr int S  = 2048;
static constexpr int D  = 512;
static constexpr int KE = 1024;   // encoder feature dim = 2*ENC_H
static constexpr int IN = 1536;   // D + KE

__device__ __forceinline__ unsigned pk2(float lo, float hi) {
    __hip_bfloat162 t = __float22bfloat162_rn(make_float2(lo, hi));
    unsigned u;
    __builtin_memcpy(&u, &t, 4);
    return u;
}

// float4 -> 4 bf16 (8 B)
__device__ __forceinline__ short4v pack4(float4 f) {
    unsigned u2[2] = { pk2(f.x, f.y), pk2(f.z, f.w) };
    short4v r;
    __builtin_memcpy(&r, u2, 8);
    return r;
}

// pack 8 fp32 -> short8 bf16
__device__ __forceinline__ short8 pack8(float4 f0, float4 f1) {
    unsigned u[4] = { pk2(f0.x, f0.y), pk2(f0.z, f0.w), pk2(f1.x, f1.y), pk2(f1.z, f1.w) };
    short8 r;
    __builtin_memcpy(&r, u, 16);
    return r;
}

__device__ __forceinline__ short8 cat44(short4v lo, short4v hi) {
    short8 r;
    __builtin_memcpy(&r, &lo, 8);
    __builtin_memcpy(((char*)&r) + 8, &hi, 8);
    return r;
}

// fast tanh via exp: (e^2x - 1)/(e^2x + 1)
__device__ __forceinline__ float tanh_fast(float x) {
    float e = __expf(2.0f * x);
    return (e - 1.0f) * __builtin_amdgcn_rcpf(e + 1.0f);
}

// ---------- kernel 0: fused prep ----------
// blocks [0,256): pack enc-part of attn_w into bf16 MFMA-B-fragment order
//   Bf layout: element (d,k) -> short8 index ((k>>4)*16 + (d>>5))*64 + (d&31) + ((k>>3)&1)*32, slot j=k&7
// blocks [256,320): u[b][d] = hidden[b]·attn_w[d,0:512] + attn_b[d]
__global__ void k_prep(const float* __restrict__ attn_w,
                       const float* __restrict__ hidden,
                       const float* __restrict__ attn_b,
                       unsigned short* __restrict__ Bf,
                       float* __restrict__ u) {
    if (blockIdx.x < 256) {
        int o = blockIdx.x * 256 + threadIdx.x;   // short8 index, 65536 total
        int l6  = o & 63;
        int grp = o >> 6;
        int d = (grp & 15) * 32 + (l6 & 31);
        int k = (grp >> 4) * 16 + (l6 >> 5) * 8;
        const float* src = attn_w + (size_t)d * IN + 512 + k;
        float4 f0 = *(const float4*)src;
        float4 f1 = *(const float4*)(src + 4);
        ((short8*)Bf)[o] = pack8(f0, f1);
    } else {
        int gid = (blockIdx.x - 256) * 256 + threadIdx.x;   // 16384 total
        int b = gid >> 9;
        int d = gid & (D - 1);
        const float* h = hidden + b * D;
        const float* w = attn_w + (size_t)d * IN;
        float acc = attn_b[d];
        for (int k = 0; k < D; k += 4) {
            float4 hv = *(const float4*)(h + k);
            float4 wv = *(const float4*)(w + k);
            acc += hv.x * wv.x + hv.y * wv.y + hv.z * wv.z + hv.w * wv.w;
        }
        u[gid] = acc;
    }
}

// ---------- kernel 2: scores via bf16 MFMA, LDS-transposed A, global B ----------
// block: 32 s x 512 d, 4 waves; wave w owns d-slice [w*128,(w+1)*128): 1 m-tile x 4 n-tiles.
// acc = 4 x f32x16 = 64 AGPRs -> with ~100 VGPRs fits 3 waves/SIMD (3 blocks/CU).
// K-chunks of 64: coalesced global float4 loads -> bf16 -> padded LDS tile (dbuf).
// LDS tile: row m (0..31), 64 bf16 of k; row stride 19 short4-units (152 B):
//   write lanes 2-way banked (free), b64 frag reads conflict-free (verified r6: conflicts=0).
#define LOADB(K, DST) do {                                     \
    _Pragma("unroll")                                          \
    for (int _jt = 0; _jt < 4; _jt++)                          \
        DST[_jt] = bb[(size_t)(K) * 1024 + _jt * 64];          \
} while (0)

__global__ __launch_bounds__(256, 3) void k_scores(
    const float* __restrict__ enc, const unsigned short* __restrict__ Bfrag,
    const float* __restrict__ u, const float* __restrict__ v_w,
    const float* __restrict__ v_b, const int* __restrict__ lengths,
    float* __restrict__ scores)
{
    __shared__ short4v ldsA[2][32 * 19];   // 2 x 4864 B
    __shared__ float sPart[4][32];

    const int b   = blockIdx.y;
    const int s0  = blockIdx.x * 32;
    const int len = lengths[b];
    if (s0 >= len) return;

    const int tid = threadIdx.x;
    const int w   = tid >> 6;     // wave 0..3
    const int l   = tid & 63;     // lane

    const float* encb = enc + ((size_t)b * S + s0) * KE;
    // staging: thread covers rows mr and mr+16, float4-col cw (16 threads/row)
    const int mr = tid >> 4;      // 0..15
    const int cw = tid & 15;      // 0..15
    const float* aG = encb + (size_t)mr * KE + cw * 4;
    const int wbase = mr * 19 + cw;

    const short8* bb = (const short8*)Bfrag + (w * 4) * 64 + l;

    f32x16 acc[4];
    #pragma unroll
    for (int jt = 0; jt < 4; jt++)
        #pragma unroll
        for (int e = 0; e < 16; e++) acc[jt][e] = 0.f;

    short8 pb[2][4];
    LOADB(0, pb[0]);
    LOADB(1, pb[1]);

    // stage chunk 0 into buf 0
    {
        float4 g0 = *(const float4*)aG;
        float4 g1 = *(const float4*)(aG + (size_t)16 * KE);
        ldsA[0][wbase]           = pack4(g0);
        ldsA[0][wbase + 16 * 19] = pack4(g1);
    }
    __syncthreads();

    // frag read base: unit = m*19 + t2*4 + (l>>5)*2, m = l&31
    const int rb0 = (l & 31) * 19 + (l >> 5) * 2;

    #pragma unroll 1
    for (int c = 0; c < 16; ++c) {
        const int buf = c & 1;
        const int cn  = (c + 1) & 15;
        // global prefetch of chunk c+1 (consumed after the barrier)
        float4 g0 = *(const float4*)(aG + cn * 64);
        float4 g1 = *(const float4*)(aG + (size_t)16 * KE + cn * 64);
        // compute chunk c
        #pragma unroll
        for (int t2 = 0; t2 < 4; ++t2) {
            const short4v* base = &ldsA[buf][t2 * 4];
            short8 a0 = cat44(base[rb0], base[rb0 + 1]);
            const int bp = t2 & 1;
            #pragma unroll
            for (int jt = 0; jt < 4; jt++)
                acc[jt] = __builtin_amdgcn_mfma_f32_32x32x16_bf16(a0, pb[bp][jt], acc[jt], 0, 0, 0);
            LOADB((c * 4 + t2 + 2) & 63, pb[bp]);
        }
        __syncthreads();
        ldsA[buf ^ 1][wbase]           = pack4(g0);
        ldsA[buf ^ 1][wbase + 16 * 19] = pack4(g1);
        __syncthreads();
    }

    // ---- epilogue: score_part = sum_d v[d]*tanh(pre + u[d]) ----
    // C/D layout (32x32): col = lane&31, row = (reg&3) + 8*(reg>>2) + 4*(lane>>5)
    float vv[4], uu[4];
    const float* ub = u + b * D;
    #pragma unroll
    for (int jt = 0; jt < 4; jt++) {
        int d = w * 128 + jt * 32 + (l & 31);
        vv[jt] = v_w[d];
        uu[jt] = ub[d];
    }
    float red[16];
    #pragma unroll
    for (int r = 0; r < 16; r++) {
        float s = 0.f;
        #pragma unroll
        for (int jt = 0; jt < 4; jt++)
            s += vv[jt] * tanh_fast(acc[jt][r] + uu[jt]);
        red[r] = s;
    }
    #pragma unroll
    for (int off = 16; off >= 1; off >>= 1)
        #pragma unroll
        for (int r = 0; r < 16; r++)
            red[r] += __shfl_xor(red[r], off);
    if ((l & 31) == 0) {
        int hb = (l >> 5) * 4;
        #pragma unroll
        for (int r = 0; r < 16; r++)
            sPart[w][(r & 3) + 8 * (r >> 2) + hb] = red[r];
    }
    __syncthreads();
    if (tid < 32)
        scores[b * S + s0 + tid] =
            sPart[0][tid] + sPart[1][tid] + sPart[2][tid] + sPart[3][tid] + v_b[0];
}

// ---------- kernel 3: masked softmax over s < len ----------
__global__ void k_softmax(const float* __restrict__ scores,
                          const int* __restrict__ lengths,
                          float* __restrict__ energy) {
    const int b = blockIdx.x;
    const int len = lengths[b];
    const int tid = threadIdx.x;
    const int lane = tid & 63, wave = tid >> 6;
    __shared__ float red[4];
    const float* sc = scores + b * S;

    float m = -INFINITY;
    for (int s = tid; s < len; s += 256) m = fmaxf(m, sc[s]);
    #pragma unroll
    for (int off = 32; off >= 1; off >>= 1) m = fmaxf(m, __shfl_xor(m, off));
    if (lane == 0) red[wave] = m;
    __syncthreads();
    m = fmaxf(fmaxf(red[0], red[1]), fmaxf(red[2], red[3]));
    __syncthreads();

    float sum = 0.f;
    for (int s = tid; s < len; s += 256) sum += __expf(sc[s] - m);
    #pragma unroll
    for (int off = 32; off >= 1; off >>= 1) sum += __shfl_xor(sum, off);
    if (lane == 0) red[wave] = sum;
    __syncthreads();
    float inv = 1.f / (red[0] + red[1] + red[2] + red[3]);

    for (int s = tid; s < len; s += 256) energy[b * S + s] = __expf(sc[s] - m) * inv;
}

// ---------- kernel 4: context[b][e] = sum_s energy[b][s]*enc[b][s][e] ----------
__global__ void k_context(const float* __restrict__ enc,
                          const float* __restrict__ energy,
                          const int* __restrict__ lengths,
                          float* __restrict__ out) {
    const int b = blockIdx.y;
    const int len = lengths[b];
    const int s0 = blockIdx.x * 128;
    if (s0 >= len) return;
    const int s1 = min(s0 + 128, len);
    const int tid = threadIdx.x;                 // 256 threads x float4 = 1024 e
    const float4* encb = (const float4*)(enc + (size_t)b * S * KE);
    const float* en = energy + b * S;
    float4 acc[8];
    #pragma unroll
    for (int i = 0; i < 8; i++) acc[i] = make_float4(0.f, 0.f, 0.f, 0.f);
    int s = s0;
    for (; s + 8 <= s1; s += 8) {
        #pragma unroll
        for (int i = 0; i < 8; i++) {
            float wgt = en[s + i];
            float4 v = encb[(size_t)(s + i) * 256 + tid];
            acc[i].x += wgt * v.x; acc[i].y += wgt * v.y;
            acc[i].z += wgt * v.z; acc[i].w += wgt * v.w;
        }
    }
    for (; s < s1; s++) {
        float wgt = en[s];
        float4 v = encb[(size_t)s * 256 + tid];
        acc[0].x += wgt * v.x; acc[0].y += wgt * v.y;
        acc[0].z += wgt * v.z; acc[0].w += wgt * v.w;
    }
    #pragma unroll
    for (int i = 1; i < 8; i++) {
        acc[0].x += acc[i].x; acc[0].y += acc[i].y;
        acc[0].z += acc[i].z; acc[0].w += acc[i].w;
    }
    float* o = out + b * KE + tid * 4;
    atomicAdd(o + 0, acc[0].x);
    atomicAdd(o + 1, acc[0].y);
    atomicAdd(o + 2, acc[0].z);
    atomicAdd(o + 3, acc[0].w);
}

extern "C" void kernel_launch(void* const* d_in, const int* in_sizes, int n_in,
                              void* d_out, int out_size, void* d_ws, size_t ws_size,
                              hipStream_t stream) {
    const float* enc    = (const float*)d_in[0];
    const float* hidden = (const float*)d_in[1];
    const int*   lengths= (const int*)d_in[2];
    const float* attn_w = (const float*)d_in[3];
    const float* attn_b = (const float*)d_in[4];
    const float* v_w    = (const float*)d_in[5];
    const float* v_b    = (const float*)d_in[6];
    float* out = (float*)d_out;

    // workspace layout (fp32 elements)
    float* ws     = (float*)d_ws;
    float* u      = ws;                     // 16384 floats
    float* scores = u + B * D;              // 65536 floats
    float* energy = scores + B * S;         // 65536 floats
    unsigned short* Bf = (unsigned short*)(energy + B * S);  // 524288 bf16 = 1MB, 16B-aligned

    (void)hipMemsetAsync(d_out, 0, (size_t)out_size * sizeof(float), stream);
    k_prep  <<<dim3(320), 256, 0, stream>>>(attn_w, hidden, attn_b, Bf, u);
    k_scores<<<dim3(S / 32, B), 256, 0, stream>>>(enc, Bf, u, v_w, v_b, lengths, scores);
    k_softmax<<<dim3(B), 256, 0, stream>>>(scores, lengths, energy);
    k_context<<<dim3(16, B), 256, 0, stream>>>(enc, energy, lengths, out);
}

// Round 8
// 451.809 us; speedup vs baseline: 1.0359x; 1.0359x over previous
//
#include <hip/hip_runtime.h>
#include <hip/hip_bf16.h>
#include <math.h>

typedef __attribute__((ext_vector_type(4))) short short4v;
typedef __attribute__((ext_vector_type(8))) short short8;
typedef __attribute__((ext_vector_type(16))) float f32x16;

static constexpr int B  = 32;
static constexpr int S  = 2048;
static constexpr int D  = 512;
static constexpr int KE = 1024;   // encoder feature dim = 2*ENC_H
static constexpr int IN = 1536;   // D + KE

__device__ __forceinline__ unsigned pk2(float lo, float hi) {
    __hip_bfloat162 t = __float22bfloat162_rn(make_float2(lo, hi));
    unsigned u;
    __builtin_memcpy(&u, &t, 4);
    return u;
}

// float4 -> 4 bf16 (8 B)
__device__ __forceinline__ short4v pack4(float4 f) {
    unsigned u2[2] = { pk2(f.x, f.y), pk2(f.z, f.w) };
    short4v r;
    __builtin_memcpy(&r, u2, 8);
    return r;
}

// pack 8 fp32 -> short8 bf16
__device__ __forceinline__ short8 pack8(float4 f0, float4 f1) {
    unsigned u[4] = { pk2(f0.x, f0.y), pk2(f0.z, f0.w), pk2(f1.x, f1.y), pk2(f1.z, f1.w) };
    short8 r;
    __builtin_memcpy(&r, u, 16);
    return r;
}

__device__ __forceinline__ short8 cat44(short4v lo, short4v hi) {
    short8 r;
    __builtin_memcpy(&r, &lo, 8);
    __builtin_memcpy(((char*)&r) + 8, &hi, 8);
    return r;
}

// fast tanh via exp: (e^2x - 1)/(e^2x + 1)
__device__ __forceinline__ float tanh_fast(float x) {
    float e = __expf(2.0f * x);
    return (e - 1.0f) * __builtin_amdgcn_rcpf(e + 1.0f);
}

// ---------- kernel 0: fused prep ----------
// blocks [0,256): pack enc-part of attn_w into bf16 MFMA-B-fragment order
//   Bf layout: element (d,k) -> short8 index ((k>>4)*16 + (d>>5))*64 + (d&31) + ((k>>3)&1)*32, slot j=k&7
// blocks [256,320): u[b][d] = hidden[b]·attn_w[d,0:512] + attn_b[d]
__global__ void k_prep(const float* __restrict__ attn_w,
                       const float* __restrict__ hidden,
                       const float* __restrict__ attn_b,
                       unsigned short* __restrict__ Bf,
                       float* __restrict__ u) {
    if (blockIdx.x < 256) {
        int o = blockIdx.x * 256 + threadIdx.x;   // short8 index, 65536 total
        int l6  = o & 63;
        int grp = o >> 6;
        int d = (grp & 15) * 32 + (l6 & 31);
        int k = (grp >> 4) * 16 + (l6 >> 5) * 8;
        const float* src = attn_w + (size_t)d * IN + 512 + k;
        float4 f0 = *(const float4*)src;
        float4 f1 = *(const float4*)(src + 4);
        ((short8*)Bf)[o] = pack8(f0, f1);
    } else {
        int gid = (blockIdx.x - 256) * 256 + threadIdx.x;   // 16384 total
        int b = gid >> 9;
        int d = gid & (D - 1);
        const float* h = hidden + b * D;
        const float* w = attn_w + (size_t)d * IN;
        float acc = attn_b[d];
        for (int k = 0; k < D; k += 4) {
            float4 hv = *(const float4*)(h + k);
            float4 wv = *(const float4*)(w + k);
            acc += hv.x * wv.x + hv.y * wv.y + hv.z * wv.z + hv.w * wv.w;
        }
        u[gid] = acc;
    }
}

// ---------- kernel 1: FUSED scores + exp + context-accumulate ----------
// block: 32 s x 512 d, 4 waves. GEMM identical to r7. Then per-row
// w = exp(score) (no max-trick: |score| <= ~23, exp fits fp32), masked by len,
// and context partials accumulated into num[b][e] / den[b] via fp32 atomics.
// enc re-read for context is L2-warm (same 128 KB the block just streamed).
#define LOADB(K, DST) do {                                     \
    _Pragma("unroll")                                          \
    for (int _jt = 0; _jt < 4; _jt++)                          \
        DST[_jt] = bb[(size_t)(K) * 1024 + _jt * 64];          \
} while (0)

__global__ __launch_bounds__(256, 3) void k_fused(
    const float* __restrict__ enc, const unsigned short* __restrict__ Bfrag,
    const float* __restrict__ u, const float* __restrict__ v_w,
    const float* __restrict__ v_b, const int* __restrict__ lengths,
    float* __restrict__ num, float* __restrict__ den)
{
    __shared__ short4v ldsA[2][32 * 19];   // 2 x 4864 B
    __shared__ float sPart[4][32];
    __shared__ float sExp[32];

    const int b   = blockIdx.y;
    const int s0  = blockIdx.x * 32;
    const int len = lengths[b];
    if (s0 >= len) return;

    const int tid = threadIdx.x;
    const int w   = tid >> 6;     // wave 0..3
    const int l   = tid & 63;     // lane

    const float* encb = enc + ((size_t)b * S + s0) * KE;
    // staging: thread covers rows mr and mr+16, float4-col cw (16 threads/row)
    const int mr = tid >> 4;      // 0..15
    const int cw = tid & 15;      // 0..15
    const float* aG = encb + (size_t)mr * KE + cw * 4;
    const int wbase = mr * 19 + cw;

    const short8* bb = (const short8*)Bfrag + (w * 4) * 64 + l;

    f32x16 acc[4];
    #pragma unroll
    for (int jt = 0; jt < 4; jt++)
        #pragma unroll
        for (int e = 0; e < 16; e++) acc[jt][e] = 0.f;

    short8 pb[2][4];
    LOADB(0, pb[0]);
    LOADB(1, pb[1]);

    // stage chunk 0 into buf 0
    {
        float4 g0 = *(const float4*)aG;
        float4 g1 = *(const float4*)(aG + (size_t)16 * KE);
        ldsA[0][wbase]           = pack4(g0);
        ldsA[0][wbase + 16 * 19] = pack4(g1);
    }
    __syncthreads();

    // frag read base: unit = m*19 + t2*4 + (l>>5)*2, m = l&31
    const int rb0 = (l & 31) * 19 + (l >> 5) * 2;

    #pragma unroll 1
    for (int c = 0; c < 16; ++c) {
        const int buf = c & 1;
        const int cn  = (c + 1) & 15;
        // global prefetch of chunk c+1 (consumed after the barrier)
        float4 g0 = *(const float4*)(aG + cn * 64);
        float4 g1 = *(const float4*)(aG + (size_t)16 * KE + cn * 64);
        // compute chunk c
        #pragma unroll
        for (int t2 = 0; t2 < 4; ++t2) {
            const short4v* base = &ldsA[buf][t2 * 4];
            short8 a0 = cat44(base[rb0], base[rb0 + 1]);
            const int bp = t2 & 1;
            #pragma unroll
            for (int jt = 0; jt < 4; jt++)
                acc[jt] = __builtin_amdgcn_mfma_f32_32x32x16_bf16(a0, pb[bp][jt], acc[jt], 0, 0, 0);
            LOADB((c * 4 + t2 + 2) & 63, pb[bp]);
        }
        __syncthreads();
        ldsA[buf ^ 1][wbase]           = pack4(g0);
        ldsA[buf ^ 1][wbase + 16 * 19] = pack4(g1);
        __syncthreads();
    }

    // ---- epilogue A: score_part = sum_d v[d]*tanh(pre + u[d]) ----
    // C/D layout (32x32): col = lane&31, row = (reg&3) + 8*(reg>>2) + 4*(lane>>5)
    float vv[4], uu[4];
    const float* ub = u + b * D;
    #pragma unroll
    for (int jt = 0; jt < 4; jt++) {
        int d = w * 128 + jt * 32 + (l & 31);
        vv[jt] = v_w[d];
        uu[jt] = ub[d];
    }
    float red[16];
    #pragma unroll
    for (int r = 0; r < 16; r++) {
        float s = 0.f;
        #pragma unroll
        for (int jt = 0; jt < 4; jt++)
            s += vv[jt] * tanh_fast(acc[jt][r] + uu[jt]);
        red[r] = s;
    }
    #pragma unroll
    for (int off = 16; off >= 1; off >>= 1)
        #pragma unroll
        for (int r = 0; r < 16; r++)
            red[r] += __shfl_xor(red[r], off);
    if ((l & 31) == 0) {
        int hb = (l >> 5) * 4;
        #pragma unroll
        for (int r = 0; r < 16; r++)
            sPart[w][(r & 3) + 8 * (r >> 2) + hb] = red[r];
    }
    __syncthreads();

    // ---- epilogue B: w = exp(score), masked; den partial ----
    if (tid < 32) {
        float sc = sPart[0][tid] + sPart[1][tid] + sPart[2][tid] + sPart[3][tid] + v_b[0];
        float wexp = (s0 + tid < len) ? __expf(sc) : 0.f;
        sExp[tid] = wexp;
        float dsum = wexp;
        #pragma unroll
        for (int off = 16; off >= 1; off >>= 1) dsum += __shfl_xor(dsum, off);
        if (tid == 0) atomicAdd(den + b, dsum);
    }
    __syncthreads();

    // ---- epilogue C: context partial: num[b][e] += sum_s w_s * enc[s][e] ----
    // thread tid covers float4 e-chunk tid; enc rows are L2-warm.
    const float4* e4 = (const float4*)encb;
    float4 cacc[4];
    #pragma unroll
    for (int j = 0; j < 4; j++) cacc[j] = make_float4(0.f, 0.f, 0.f, 0.f);
    #pragma unroll
    for (int i = 0; i < 8; i++) {
        #pragma unroll
        for (int j = 0; j < 4; j++) {
            float wgt = sExp[i * 4 + j];
            float4 v = e4[(size_t)(i * 4 + j) * 256 + tid];
            cacc[j].x += wgt * v.x; cacc[j].y += wgt * v.y;
            cacc[j].z += wgt * v.z; cacc[j].w += wgt * v.w;
        }
    }
    #pragma unroll
    for (int j = 1; j < 4; j++) {
        cacc[0].x += cacc[j].x; cacc[0].y += cacc[j].y;
        cacc[0].z += cacc[j].z; cacc[0].w += cacc[j].w;
    }
    float* o = num + b * KE + tid * 4;
    atomicAdd(o + 0, cacc[0].x);
    atomicAdd(o + 1, cacc[0].y);
    atomicAdd(o + 2, cacc[0].z);
    atomicAdd(o + 3, cacc[0].w);
}

// ---------- kernel 2: out = num / den ----------
__global__ void k_norm(const float* __restrict__ num, const float* __restrict__ den,
                       float* __restrict__ out) {
    int b = blockIdx.x;
    int t = threadIdx.x;
    float inv = 1.f / den[b];
    float4 v = ((const float4*)(num + b * KE))[t];
    v.x *= inv; v.y *= inv; v.z *= inv; v.w *= inv;
    ((float4*)(out + b * KE))[t] = v;
}

extern "C" void kernel_launch(void* const* d_in, const int* in_sizes, int n_in,
                              void* d_out, int out_size, void* d_ws, size_t ws_size,
                              hipStream_t stream) {
    const float* enc    = (const float*)d_in[0];
    const float* hidden = (const float*)d_in[1];
    const int*   lengths= (const int*)d_in[2];
    const float* attn_w = (const float*)d_in[3];
    const float* attn_b = (const float*)d_in[4];
    const float* v_w    = (const float*)d_in[5];
    const float* v_b    = (const float*)d_in[6];
    float* out = (float*)d_out;

    // workspace layout (fp32 elements)
    float* ws  = (float*)d_ws;
    float* u   = ws;                        // 16384 floats
    float* num = u + B * D;                 // B*KE = 32768 floats
    float* den = num + B * KE;              // 32 floats
    unsigned short* Bf = (unsigned short*)(den + 32);  // 524288 bf16 = 1MB (offset 196736 B, 16B-aligned)

    // zero num+den (poisoned 0xAA by harness before every launch)
    (void)hipMemsetAsync(num, 0, (size_t)(B * KE + B) * sizeof(float), stream);
    k_prep <<<dim3(320), 256, 0, stream>>>(attn_w, hidden, attn_b, Bf, u);
    k_fused<<<dim3(S / 32, B), 256, 0, stream>>>(enc, Bf, u, v_w, v_b, lengths, num, den);
    k_norm <<<dim3(B), 256, 0, stream>>>(num, den, out);
}

// Round 9
// 437.868 us; speedup vs baseline: 1.0689x; 1.0318x over previous
//
#include <hip/hip_runtime.h>
#include <hip/hip_bf16.h>
#include <math.h>

typedef __attribute__((ext_vector_type(4))) short short4v;
typedef __attribute__((ext_vector_type(8))) short short8;
typedef __attribute__((ext_vector_type(16))) float f32x16;

static constexpr int B  = 32;
static constexpr int S  = 2048;
static constexpr int D  = 512;
static constexpr int KE = 1024;   // encoder feature dim = 2*ENC_H
static constexpr int IN = 1536;   // D + KE

__device__ __forceinline__ unsigned pk2(float lo, float hi) {
    __hip_bfloat162 t = __float22bfloat162_rn(make_float2(lo, hi));
    unsigned u;
    __builtin_memcpy(&u, &t, 4);
    return u;
}

__device__ __forceinline__ short4v pack4(float4 f) {
    unsigned u2[2] = { pk2(f.x, f.y), pk2(f.z, f.w) };
    short4v r;
    __builtin_memcpy(&r, u2, 8);
    return r;
}

__device__ __forceinline__ short8 pack8(float4 f0, float4 f1) {
    unsigned u[4] = { pk2(f0.x, f0.y), pk2(f0.z, f0.w), pk2(f1.x, f1.y), pk2(f1.z, f1.w) };
    short8 r;
    __builtin_memcpy(&r, u, 16);
    return r;
}

__device__ __forceinline__ short8 cat44(short4v lo, short4v hi) {
    short8 r;
    __builtin_memcpy(&r, &lo, 8);
    __builtin_memcpy(((char*)&r) + 8, &hi, 8);
    return r;
}

// fast tanh via exp: (e^2x - 1)/(e^2x + 1)
__device__ __forceinline__ float tanh_fast(float x) {
    float e = __expf(2.0f * x);
    return (e - 1.0f) * __builtin_amdgcn_rcpf(e + 1.0f);
}

// ---------- kernel 0: fused prep (B-frag pack + u projection) ----------
__global__ void k_prep(const float* __restrict__ attn_w,
                       const float* __restrict__ hidden,
                       const float* __restrict__ attn_b,
                       unsigned short* __restrict__ Bf,
                       float* __restrict__ u) {
    if (blockIdx.x < 256) {
        int o = blockIdx.x * 256 + threadIdx.x;   // short8 index, 65536 total
        int l6  = o & 63;
        int grp = o >> 6;
        int d = (grp & 15) * 32 + (l6 & 31);
        int k = (grp >> 4) * 16 + (l6 >> 5) * 8;
        const float* src = attn_w + (size_t)d * IN + 512 + k;
        float4 f0 = *(const float4*)src;
        float4 f1 = *(const float4*)(src + 4);
        ((short8*)Bf)[o] = pack8(f0, f1);
    } else {
        int gid = (blockIdx.x - 256) * 256 + threadIdx.x;   // 16384 total
        int b = gid >> 9;
        int d = gid & (D - 1);
        const float* h = hidden + b * D;
        const float* w = attn_w + (size_t)d * IN;
        float acc = attn_b[d];
        for (int k = 0; k < D; k += 4) {
            float4 hv = *(const float4*)(h + k);
            float4 wv = *(const float4*)(w + k);
            acc += hv.x * wv.x + hv.y * wv.y + hv.z * wv.z + hv.w * wv.w;
        }
        u[gid] = acc;
    }
}

// ---------- kernel 1: FUSED scores + exp + context-accumulate ----------
// block: 64 s x 512 d, 4 waves; wave w owns d-slice [w*128,(w+1)*128):
// 2 m-tiles x 4 n-tiles (B-frag reused across both m-tiles -> halves L1 B-feed).
// Single barrier per K-chunk: iter c writes chunk c into buf c&1 while
// computing chunk c-1 from buf (c-1)&1; barrier at loop top provides both
// write->read (prev chunk) and read->overwrite (chunk c-2) ordering.
#define LOADB(K, DST) do {                                     \
    _Pragma("unroll")                                          \
    for (int _jt = 0; _jt < 4; _jt++)                          \
        DST[_jt] = bb[(size_t)(K) * 1024 + _jt * 64];          \
} while (0)

__global__ __launch_bounds__(256, 2) void k_fused(
    const float* __restrict__ enc, const unsigned short* __restrict__ Bfrag,
    const float* __restrict__ u, const float* __restrict__ v_w,
    const float* __restrict__ v_b, const int* __restrict__ lengths,
    float* __restrict__ num, float* __restrict__ den)
{
    __shared__ short4v ldsA[2][64 * 19];   // 2 x 9728 B, row stride 19 units (conflict-free, r6-verified)
    __shared__ float sPart[4][64];
    __shared__ float sExp[64];

    const int b   = blockIdx.y;
    const int s0  = blockIdx.x * 64;
    const int len = lengths[b];
    if (s0 >= len) return;

    const int tid = threadIdx.x;
    const int w   = tid >> 6;     // wave 0..3
    const int l   = tid & 63;     // lane

    const float* encb = enc + ((size_t)b * S + s0) * KE;
    // staging: thread covers rows mr+16*i (i=0..3), float4-col cw (16 thr/row)
    const int mr = tid >> 4;      // 0..15
    const int cw = tid & 15;      // 0..15
    const float* aG = encb + (size_t)mr * KE + cw * 4;
    const int wbase = mr * 19 + cw;

    const short8* bb = (const short8*)Bfrag + (w * 4) * 64 + l;

    f32x16 acc[2][4];
    #pragma unroll
    for (int mt = 0; mt < 2; mt++)
        #pragma unroll
        for (int jt = 0; jt < 4; jt++)
            #pragma unroll
            for (int e = 0; e < 16; e++) acc[mt][jt][e] = 0.f;

    short8 pb[2][4];
    LOADB(0, pb[0]);
    LOADB(1, pb[1]);

    // prefetch chunk 0 into regs
    float4 g[4];
    #pragma unroll
    for (int i = 0; i < 4; i++) g[i] = *(const float4*)(aG + (size_t)i * 16 * KE);

    // frag read base: unit = m*19 + t2*4 + (l>>5)*2, m = l&31 (+32 for mt=1)
    const int rb0 = (l & 31) * 19 + (l >> 5) * 2;
    const int rb1 = rb0 + 32 * 19;

    #pragma unroll 1
    for (int c = 0; c <= 16; ++c) {
        __syncthreads();
        if (c < 16) {
            // write chunk c (in g) into buf c&1
            #pragma unroll
            for (int i = 0; i < 4; i++)
                ldsA[c & 1][wbase + i * 16 * 19] = pack4(g[i]);
            // prefetch chunk c+1
            if (c < 15) {
                #pragma unroll
                for (int i = 0; i < 4; i++)
                    g[i] = *(const float4*)(aG + (size_t)i * 16 * KE + (c + 1) * 64);
            }
        }
        if (c > 0) {
            const int buf = (c - 1) & 1;
            #pragma unroll
            for (int t2 = 0; t2 < 4; ++t2) {
                const short4v* base = &ldsA[buf][t2 * 4];
                short8 a0 = cat44(base[rb0], base[rb0 + 1]);
                short8 a1 = cat44(base[rb1], base[rb1 + 1]);
                const int bp = t2 & 1;
                #pragma unroll
                for (int jt = 0; jt < 4; jt++) {
                    acc[0][jt] = __builtin_amdgcn_mfma_f32_32x32x16_bf16(a0, pb[bp][jt], acc[0][jt], 0, 0, 0);
                    acc[1][jt] = __builtin_amdgcn_mfma_f32_32x32x16_bf16(a1, pb[bp][jt], acc[1][jt], 0, 0, 0);
                }
                LOADB(((c - 1) * 4 + t2 + 2) & 63, pb[bp]);
            }
        }
    }

    // ---- epilogue A: score_part = sum_d v[d]*tanh(pre + u[d]) ----
    // C/D layout (32x32): col = lane&31, row = (reg&3) + 8*(reg>>2) + 4*(lane>>5)
    float vv[4], uu[4];
    const float* ub = u + b * D;
    #pragma unroll
    for (int jt = 0; jt < 4; jt++) {
        int d = w * 128 + jt * 32 + (l & 31);
        vv[jt] = v_w[d];
        uu[jt] = ub[d];
    }
    float red[2][16];
    #pragma unroll
    for (int mt = 0; mt < 2; mt++)
        #pragma unroll
        for (int r = 0; r < 16; r++) {
            float s = 0.f;
            #pragma unroll
            for (int jt = 0; jt < 4; jt++)
                s += vv[jt] * tanh_fast(acc[mt][jt][r] + uu[jt]);
            red[mt][r] = s;
        }
    #pragma unroll
    for (int off = 16; off >= 1; off >>= 1)
        #pragma unroll
        for (int mt = 0; mt < 2; mt++)
            #pragma unroll
            for (int r = 0; r < 16; r++)
                red[mt][r] += __shfl_xor(red[mt][r], off);
    if ((l & 31) == 0) {
        int hb = (l >> 5) * 4;
        #pragma unroll
        for (int mt = 0; mt < 2; mt++)
            #pragma unroll
            for (int r = 0; r < 16; r++)
                sPart[w][mt * 32 + (r & 3) + 8 * (r >> 2) + hb] = red[mt][r];
    }
    __syncthreads();

    // ---- epilogue B: w = exp(score) (|score|<=~23, no max needed), masked; den ----
    if (tid < 64) {
        float sc = sPart[0][tid] + sPart[1][tid] + sPart[2][tid] + sPart[3][tid] + v_b[0];
        float wexp = (s0 + tid < len) ? __expf(sc) : 0.f;
        sExp[tid] = wexp;
        #pragma unroll
        for (int off = 32; off >= 1; off >>= 1) wexp += __shfl_xor(wexp, off);
        if (tid == 0) atomicAdd(den + b, wexp);
    }
    __syncthreads();

    // ---- epilogue C: num[b][e] += sum_s w_s * enc[s][e] (enc L2-warm) ----
    const float4* e4 = (const float4*)encb;
    float4 cacc[4];
    #pragma unroll
    for (int j = 0; j < 4; j++) cacc[j] = make_float4(0.f, 0.f, 0.f, 0.f);
    #pragma unroll
    for (int i = 0; i < 16; i++) {
        #pragma unroll
        for (int j = 0; j < 4; j++) {
            float wgt = sExp[i * 4 + j];
            float4 v = e4[(size_t)(i * 4 + j) * 256 + tid];
            cacc[j].x += wgt * v.x; cacc[j].y += wgt * v.y;
            cacc[j].z += wgt * v.z; cacc[j].w += wgt * v.w;
        }
    }
    #pragma unroll
    for (int j = 1; j < 4; j++) {
        cacc[0].x += cacc[j].x; cacc[0].y += cacc[j].y;
        cacc[0].z += cacc[j].z; cacc[0].w += cacc[j].w;
    }
    float* o = num + b * KE + tid * 4;
    atomicAdd(o + 0, cacc[0].x);
    atomicAdd(o + 1, cacc[0].y);
    atomicAdd(o + 2, cacc[0].z);
    atomicAdd(o + 3, cacc[0].w);
}

// ---------- kernel 2: out = num / den ----------
__global__ void k_norm(const float* __restrict__ num, const float* __restrict__ den,
                       float* __restrict__ out) {
    int b = blockIdx.x;
    int t = threadIdx.x;
    float inv = 1.f / den[b];
    float4 v = ((const float4*)(num + b * KE))[t];
    v.x *= inv; v.y *= inv; v.z *= inv; v.w *= inv;
    ((float4*)(out + b * KE))[t] = v;
}

extern "C" void kernel_launch(void* const* d_in, const int* in_sizes, int n_in,
                              void* d_out, int out_size, void* d_ws, size_t ws_size,
                              hipStream_t stream) {
    const float* enc    = (const float*)d_in[0];
    const float* hidden = (const float*)d_in[1];
    const int*   lengths= (const int*)d_in[2];
    const float* attn_w = (const float*)d_in[3];
    const float* attn_b = (const float*)d_in[4];
    const float* v_w    = (const float*)d_in[5];
    const float* v_b    = (const float*)d_in[6];
    float* out = (float*)d_out;

    // workspace layout (fp32 elements)
    float* ws  = (float*)d_ws;
    float* u   = ws;                        // 16384 floats
    float* num = u + B * D;                 // B*KE = 32768 floats
    float* den = num + B * KE;              // 32 floats
    unsigned short* Bf = (unsigned short*)(den + 32);  // 524288 bf16 = 1MB (16B-aligned)

    (void)hipMemsetAsync(num, 0, (size_t)(B * KE + B) * sizeof(float), stream);
    k_prep <<<dim3(320), 256, 0, stream>>>(attn_w, hidden, attn_b, Bf, u);
    k_fused<<<dim3(S / 64, B), 256, 0, stream>>>(enc, Bf, u, v_w, v_b, lengths, num, den);
    k_norm <<<dim3(B), 256, 0, stream>>>(num, den, out);
}